// Round 6
// baseline (233.655 us; speedup 1.0000x reference)
//
#include <hip/hip_runtime.h>

#define PH 7
#define PW 7
#define SR 2
#define SY (PH * SR)   // 14
#define SX (PW * SR)   // 14
#define CH 256
#define FH 200
#define FW 272
#define BINS (PH * PW) // 49
#define NPIX (FH * FW) // 54400

__device__ __forceinline__ unsigned short f2bf(float f) {
    unsigned x = __float_as_uint(f);
    return (unsigned short)((x + 0x7fffu + ((x >> 16) & 1u)) >> 16);
}
__device__ __forceinline__ float bflo(unsigned u) { return __uint_as_float(u << 16); }
__device__ __forceinline__ float bfhi(unsigned u) { return __uint_as_float(u & 0xffff0000u); }

// ---------- Pass 1: feat [B,C,H,W] fp32 -> featT [B,H,W,C] bf16 ----------
// One block per (b*FH+h, c-group-of-32). LDS 18.5 KB -> 8 blocks/CU.
// A 272-float row is 68 float4; 8 lanes/row x 9 iters (masked <68) covers it.
__global__ __launch_bounds__(256) void transpose_kernel(
    const float* __restrict__ feat, unsigned short* __restrict__ featT) {
    __shared__ unsigned short tile[FW][34];   // 18496 B (pad 32->34)
    const int t  = threadIdx.x;
    const int bh = blockIdx.x;                // b*FH + h
    const int c0 = blockIdx.y * 32;
    const int b  = bh / FH;
    const int h  = bh % FH;

    // Load: 8 lanes per channel row, float4 each; 68 float4 per 1088 B row
    const int cl  = t >> 3;                   // 0..31
    const int wq0 = t & 7;
    const float* __restrict__ src =
        feat + (size_t)b * CH * NPIX + (size_t)(c0 + cl) * NPIX + (size_t)h * FW;
    #pragma unroll
    for (int k = 0; k < 9; ++k) {
        const int fidx = wq0 + 8 * k;         // 0..71, valid < 68
        if (fidx < 68) {
            const float4 v = *(const float4*)(src + fidx * 4);
            const int w = fidx * 4;
            tile[w + 0][cl] = f2bf(v.x);
            tile[w + 1][cl] = f2bf(v.y);
            tile[w + 2][cl] = f2bf(v.z);
            tile[w + 3][cl] = f2bf(v.w);
        }
    }
    __syncthreads();

    // Store: per w, 32 bf16 = 16 dwords = 64 B aligned chunk (no RMW)
    const int cd = t & 15;                    // c-pair 0..15
    const int wl = t >> 4;                    // 0..15
    unsigned* __restrict__ dstu = (unsigned*)featT;
    const size_t pixbase = (size_t)bh * FW;
    #pragma unroll
    for (int k = 0; k < 17; ++k) {
        const int w = wl + 16 * k;            // 272 = 16*17
        const unsigned p = *(const unsigned*)&tile[w][2 * cd];
        dstu[(pixbase + w) * (CH / 2) + (c0 >> 1) + cd] = p;
    }
}

// ---------- Pass 2: ROIAlign on channels-last bf16 featT ----------
// 2 blocks per ROI (channel halves of 128). LDS ~12.8 KB -> 8 blocks/CU.
__global__ __launch_bounds__(256) void roialign_cl_kernel(
    const unsigned short* __restrict__ featT,
    const float* __restrict__ rois,
    float* __restrict__ out, int N) {
    __shared__ int   s_yl[SY], s_yh[SY];             // offsets in DWORDS
    __shared__ float s_ly[SY], s_hy[SY];             // 0.5*weight, validity folded
    __shared__ int   s_xl[SX], s_xh[SX];
    __shared__ float s_lx[SX], s_hx[SX];
    __shared__ unsigned short s_out16[128 * BINS];   // 12544 B

    const int n    = blockIdx.x >> 1;
    const int half = blockIdx.x & 1;
    const int tid  = threadIdx.x;
    const float* __restrict__ roi = rois + (size_t)n * 5;

    if (tid < SY + SX) {
        const bool isy = (tid < SY);
        const int  idx = isy ? tid : tid - SY;
        const int  lim = isy ? FH : FW;
        const float start = (isy ? roi[2] : roi[1]) * 0.25f;
        const float end_  = (isy ? roi[4] : roi[3]) * 0.25f;
        const float len   = fmaxf(end_ - start, 1.0f);
        const float binsz = len * (isy ? (1.0f / PH) : (1.0f / PW));
        const float s = start + ((float)idx + 0.5f) * (1.0f / SR) * binsz;
        const float valid = (s > -1.0f && s < (float)lim) ? 0.5f : 0.0f; // fold 1/SR avg
        const float cc = fminf(fmaxf(s, 0.0f), (float)(lim - 1));
        const int   lo = (int)floorf(cc);
        const int   hi = min(lo + 1, lim - 1);
        const float l  = (cc - (float)lo) * valid;
        const float hw = (1.0f - (cc - (float)lo)) * valid;
        const int   rowstride = FW * (CH / 2);       // dwords per y
        if (isy) { s_yl[idx] = lo * rowstride; s_yh[idx] = hi * rowstride;
                   s_ly[idx] = l; s_hy[idx] = hw; }
        else     { s_xl[idx] = lo * (CH / 2);  s_xh[idx] = hi * (CH / 2);
                   s_lx[idx] = l; s_hx[idx] = hw; }
    }
    __syncthreads();

    const int b = (int)roi[0];
    const int q = tid & 31;               // channel-quad within half: c_local = 4q
    const int g = tid >> 5;               // 0..7 bin group
    const unsigned* __restrict__ fbu =
        (const unsigned*)featT + (size_t)b * (FH * FW * (CH / 2)) + half * 64 + q * 2;

    const int bstart = g * 6;
    const int bend   = (g == 7) ? 49 : bstart + 6;

    #pragma unroll 2
    for (int bin = bstart; bin < bend; ++bin) {
        const int ph = bin / 7;
        const int pw = bin - ph * 7;
        const int sy = ph * SR, sx = pw * SR;
        float a0 = 0.f, a1 = 0.f, a2 = 0.f, a3 = 0.f;
        #pragma unroll
        for (int i = 0; i < SR; ++i) {
            const int   yo0 = s_yl[sy + i], yo1 = s_yh[sy + i];
            const float wy1 = s_ly[sy + i], wy0 = s_hy[sy + i];
            #pragma unroll
            for (int j = 0; j < SR; ++j) {
                const int   xo0 = s_xl[sx + j], xo1 = s_xh[sx + j];
                const float wx1 = s_lx[sx + j], wx0 = s_hx[sx + j];
                const uint2 u00 = *(const uint2*)(fbu + yo0 + xo0);
                const uint2 u01 = *(const uint2*)(fbu + yo0 + xo1);
                const uint2 u10 = *(const uint2*)(fbu + yo1 + xo0);
                const uint2 u11 = *(const uint2*)(fbu + yo1 + xo1);
                const float w00 = wy0 * wx0, w01 = wy0 * wx1;
                const float w10 = wy1 * wx0, w11 = wy1 * wx1;
                a0 += w00 * bflo(u00.x) + w01 * bflo(u01.x) + w10 * bflo(u10.x) + w11 * bflo(u11.x);
                a1 += w00 * bfhi(u00.x) + w01 * bfhi(u01.x) + w10 * bfhi(u10.x) + w11 * bfhi(u11.x);
                a2 += w00 * bflo(u00.y) + w01 * bflo(u01.y) + w10 * bflo(u10.y) + w11 * bflo(u11.y);
                a3 += w00 * bfhi(u00.y) + w01 * bfhi(u01.y) + w10 * bfhi(u10.y) + w11 * bfhi(u11.y);
            }
        }
        const int c4 = q * 4;             // local channel within the half
        s_out16[(c4 + 0) * BINS + bin] = f2bf(a0);
        s_out16[(c4 + 1) * BINS + bin] = f2bf(a1);
        s_out16[(c4 + 2) * BINS + bin] = f2bf(a2);
        s_out16[(c4 + 3) * BINS + bin] = f2bf(a3);
    }
    __syncthreads();

    // Coalesced flush: 128ch*49bins = 3136 bf16 pairs -> float2 stores
    float2* __restrict__ outn2 =
        (float2*)(out + (size_t)n * (CH * BINS) + half * (128 * BINS));
    const unsigned* __restrict__ s32 = (const unsigned*)s_out16;
    #pragma unroll
    for (int k = 0; k < 13; ++k) {
        const int p = k * 256 + tid;      // pair index, < 3136
        if (p < 3136) {
            const unsigned u = s32[p];
            outn2[p] = make_float2(bflo(u), bfhi(u));
        }
    }
}

// ---------- Fallback (fp32, no workspace) ----------
__global__ __launch_bounds__(256) void roialign_kernel(
    const float* __restrict__ feat,
    const float* __restrict__ rois,
    float* __restrict__ out, int N) {
    __shared__ int   s_yl[SY], s_yh[SY];
    __shared__ float s_ly[SY], s_hy[SY];
    __shared__ int   s_xl[SX], s_xh[SX];
    __shared__ float s_lx[SX], s_hx[SX];
    __shared__ float s_out[CH * BINS];

    const int n   = blockIdx.x;
    const int tid = threadIdx.x;
    const float* __restrict__ roi = rois + (size_t)n * 5;

    if (tid < SY + SX) {
        const bool isy = (tid < SY);
        const int  idx = isy ? tid : tid - SY;
        const int  lim = isy ? FH : FW;
        const float start = (isy ? roi[2] : roi[1]) * 0.25f;
        const float end_  = (isy ? roi[4] : roi[3]) * 0.25f;
        const float len   = fmaxf(end_ - start, 1.0f);
        const float binsz = len * (isy ? (1.0f / PH) : (1.0f / PW));
        const float s = start + ((float)idx + 0.5f) * (1.0f / SR) * binsz;
        const float valid = (s > -1.0f && s < (float)lim) ? 1.0f : 0.0f;
        const float cc = fminf(fmaxf(s, 0.0f), (float)(lim - 1));
        const int   lo = (int)floorf(cc);
        const int   hi = min(lo + 1, lim - 1);
        const float l  = (cc - (float)lo) * valid;
        const float hw = (1.0f - (cc - (float)lo)) * valid;
        if (isy) { s_yl[idx] = lo; s_yh[idx] = hi; s_ly[idx] = l; s_hy[idx] = hw; }
        else     { s_xl[idx] = lo; s_xh[idx] = hi; s_lx[idx] = l; s_hx[idx] = hw; }
    }
    __syncthreads();

    const int b = (int)roi[0];
    const int c = tid;
    const float* __restrict__ fp = feat + ((size_t)b * CH + c) * (size_t)NPIX;

    #pragma unroll 1
    for (int ph = 0; ph < PH; ++ph) {
        const int sy0 = ph * SR;
        const float* r00 = fp + s_yl[sy0] * FW;
        const float* r01 = fp + s_yh[sy0] * FW;
        const float* r10 = fp + s_yl[sy0 + 1] * FW;
        const float* r11 = fp + s_yh[sy0 + 1] * FW;
        const float ly0 = s_ly[sy0],     hy0 = s_hy[sy0];
        const float ly1 = s_ly[sy0 + 1], hy1 = s_hy[sy0 + 1];
        for (int pw = 0; pw < PW; ++pw) {
            const int sx0 = pw * SR;
            float acc = 0.0f;
            #pragma unroll
            for (int j = 0; j < SR; ++j) {
                const int   xl = s_xl[sx0 + j], xh = s_xh[sx0 + j];
                const float lx = s_lx[sx0 + j], hx = s_hx[sx0 + j];
                acc += hy0 * (hx * r00[xl] + lx * r00[xh])
                     + ly0 * (hx * r01[xl] + lx * r01[xh]);
                acc += hy1 * (hx * r10[xl] + lx * r10[xh])
                     + ly1 * (hx * r11[xl] + lx * r11[xh]);
            }
            s_out[c * BINS + ph * PW + pw] = acc * 0.25f;
        }
    }
    __syncthreads();

    float* __restrict__ outn = out + (size_t)n * (CH * BINS);
    #pragma unroll
    for (int k = 0; k < BINS; ++k) {
        const int idx = k * 256 + tid;
        outn[idx] = s_out[idx];
    }
}

extern "C" void kernel_launch(void* const* d_in, const int* in_sizes, int n_in,
                              void* d_out, int out_size, void* d_ws, size_t ws_size,
                              hipStream_t stream) {
    const float* feat = (const float*)d_in[0];
    const float* rois = (const float*)d_in[1];
    float* out = (float*)d_out;
    const int N = in_sizes[1] / 5;
    const int B = in_sizes[0] / (CH * NPIX);
    const size_t need = (size_t)B * CH * NPIX * sizeof(unsigned short);

    if (ws_size >= need) {
        unsigned short* featT = (unsigned short*)d_ws;
        dim3 tgrid(B * FH, CH / 32);
        transpose_kernel<<<tgrid, 256, 0, stream>>>(feat, featT);
        roialign_cl_kernel<<<2 * N, 256, 0, stream>>>(featT, rois, out, N);
    } else {
        roialign_kernel<<<N, 256, 0, stream>>>(feat, rois, out, N);
    }
}